// Round 3
// baseline (526.726 us; speedup 1.0000x reference)
//
#include <hip/hip_runtime.h>
#include <math.h>
#include <float.h>

#define B_ 1024
#define R_ 12
#define N_ 2048

// ---------------------------------------------------------------------------
// Kernel 1: per (b,r) — intensity gate, Q MLP, fold Wk2/bk2 into the query:
//   Qp[32] = Wk2 @ Q,  c = Q . bk2.   Writes intensity to d_out tail.
// Threads with idx < N_ additionally pack the 12 freq-mask bits per LED.
// ---------------------------------------------------------------------------
__global__ void __launch_bounds__(256) prep_kernel(
    const float* __restrict__ rss,                       // [B*R]
    const float* __restrict__ Wg1, const float* __restrict__ bg1,
    const float* __restrict__ Wg2, const float* __restrict__ bg2,
    const float* __restrict__ Wq1, const float* __restrict__ bq1,
    const float* __restrict__ Wq2, const float* __restrict__ bq2,
    const float* __restrict__ Wk2, const float* __restrict__ bk2,
    const int*   __restrict__ mask,                      // [R,N]
    float* __restrict__ qp,                              // [B*R, 32]
    float* __restrict__ cc,                              // [B*R]
    int*   __restrict__ maskbits,                        // [N]
    float* __restrict__ inten_out)                       // [B*R]
{
    int idx = blockIdx.x * 256 + threadIdx.x;
    if (idx >= B_ * R_) return;

    // ---- pack freq mask bits (one pass, threads 0..N-1)
    if (idx < N_) {
        int bits = 0;
#pragma unroll
        for (int r = 0; r < R_; r++) bits |= (mask[r * N_ + idx] != 0) << r;
        maskbits[idx] = bits;
    }

    float x = rss[idx];
    float hard = (x > 0.5f) ? 1.0f : 0.0f;

    // gate MLP 1->16->1 + sigmoid
    float s2 = bg2[0];
#pragma unroll
    for (int i = 0; i < 16; i++) {
        float t = fmaxf(x * Wg1[i] + bg1[i], 0.0f);
        s2 += t * Wg2[i];
    }
    float gate = 1.0f / (1.0f + __expf(-s2));
    float iw = hard * gate;
    inten_out[idx] = iw;

    float xm = x * iw;

    // Q hidden 1->32
    float h1[32];
#pragma unroll
    for (int i = 0; i < 32; i++) h1[i] = fmaxf(xm * Wq1[i] + bq1[i], 0.0f);

    // q[d] = h1 . Wq2[:,d] + bq2[d];  Qp[j] = sum_d Wk2[j,d]*q[d];  c = q.bk2
    float Qp[32];
#pragma unroll
    for (int j = 0; j < 32; j++) Qp[j] = 0.0f;
    float c = 0.0f;
    for (int d = 0; d < 64; d++) {
        float q = bq2[d];
#pragma unroll
        for (int i = 0; i < 32; i++) q += h1[i] * Wq2[i * 64 + d];
        c += q * bk2[d];
#pragma unroll
        for (int j = 0; j < 32; j++) Qp[j] += Wk2[j * 64 + d] * q;
    }

    float* o = qp + (size_t)idx * 32;
#pragma unroll
    for (int j = 0; j < 32; j++) o[j] = Qp[j];
    cc[idx] = c;
}

// ---------------------------------------------------------------------------
// Kernel 2: one block per batch b.  512 threads; thread t owns LEDs
// n = 4t..4t+3 (all accesses float4/int4).  Weights / Qp / c read with
// wave-uniform indices -> s_load, SGPR operands on the FMAs.  Scores stay in
// registers; fused block-wide softmax; float4 coalesced writes.
// ---------------------------------------------------------------------------
__global__ void __launch_bounds__(512) main_kernel(
    const float* __restrict__ ledf,   // [B,N,8]
    const float* __restrict__ ledp,   // [B,N,3]
    const float* __restrict__ prevp,  // [B,3]
    const int*   __restrict__ maskbits, // [N]
    const float* __restrict__ Wk1,    // [11,32]
    const float* __restrict__ bk1,    // [32]
    const float* __restrict__ qp,     // [B*R,32]
    const float* __restrict__ cc,     // [B*R]
    const float* __restrict__ sigp,   // [1]
    float* __restrict__ out)          // [B,R,N]
{
    const int b = blockIdx.x;
    const int tid = threadIdx.x;
    const int lane = tid & 63;
    const int wave = tid >> 6;
    const int n0 = tid * 4;

    __shared__ float red[8 * 12];     // softmax reduction scratch only

    const float* __restrict__ qpb = qp + (size_t)b * 12 * 32;  // uniform base
    const float* __restrict__ ccb = cc + b * 12;

    const float sig = sigp[0];
    const float nf = -0.5f / (sig * sig);
    const float p0 = prevp[b * 3 + 0];
    const float p1 = prevp[b * 3 + 1];
    const float p2 = prevp[b * 3 + 2];

    // ---- vectorized per-thread loads (contiguous 4 LEDs)
    const float4* pf = reinterpret_cast<const float4*>(ledf + ((size_t)b * N_ + n0) * 8);
    const float4* pp = reinterpret_cast<const float4*>(ledp + ((size_t)b * N_ + n0) * 3);
    const float4 pa = pp[0], pb = pp[1], pc = pp[2];
    const float px[4] = {pa.x, pa.w, pb.z, pc.y};
    const float py[4] = {pa.y, pb.x, pb.w, pc.z};
    const float pz[4] = {pa.z, pb.y, pc.x, pc.w};
    const int4 mb4 = *reinterpret_cast<const int4*>(maskbits + n0);
    const int mbits[4] = {mb4.x, mb4.y, mb4.z, mb4.w};

    float sc[12][4];

#pragma unroll
    for (int l = 0; l < 4; l++) {
        const float4 f0 = pf[l * 2];
        const float4 f1 = pf[l * 2 + 1];
        const float xf[11] = {f0.x, f0.y, f0.z, f0.w,
                              f1.x, f1.y, f1.z, f1.w, px[l], py[l], pz[l]};

        // K hidden layer: h[i] = relu(bk1[i] + sum_j xf[j]*Wk1[j,i])
        float h[32];
#pragma unroll
        for (int i = 0; i < 32; i++) {
            float a = bk1[i];                      // uniform -> SGPR
#pragma unroll
            for (int j = 0; j < 11; j++) a += xf[j] * Wk1[j * 32 + i];
            h[i] = fmaxf(a, 0.0f);
        }

        const float dx = p0 - px[l], dy = p1 - py[l], dz = p2 - pz[l];
        const float bias = nf * (dx * dx + dy * dy + dz * dz);

#pragma unroll
        for (int r = 0; r < 12; r++) {
            float a = ccb[r] + bias;               // uniform -> SGPR
            const float* __restrict__ qr = qpb + r * 32;
#pragma unroll
            for (int j = 0; j < 32; j++) a += h[j] * qr[j];  // uniform -> SGPR
            sc[r][l] = ((mbits[l] >> r) & 1) ? a : -FLT_MAX;
        }
    }

    // ---- block-wide max per row r
    float m[12];
#pragma unroll
    for (int r = 0; r < 12; r++) {
        float v = fmaxf(fmaxf(sc[r][0], sc[r][1]), fmaxf(sc[r][2], sc[r][3]));
#pragma unroll
        for (int off = 32; off >= 1; off >>= 1) v = fmaxf(v, __shfl_xor(v, off));
        m[r] = v;
    }
    if (lane == 0) {
#pragma unroll
        for (int r = 0; r < 12; r++) red[wave * 12 + r] = m[r];
    }
    __syncthreads();
#pragma unroll
    for (int r = 0; r < 12; r++) {
        float v = red[r];
#pragma unroll
        for (int w = 1; w < 8; w++) v = fmaxf(v, red[w * 12 + r]);
        m[r] = v;
    }
    __syncthreads();  // red about to be reused

    // ---- exp + block-wide sum per row r
    float s[12];
#pragma unroll
    for (int r = 0; r < 12; r++) {
        float acc = 0.0f;
#pragma unroll
        for (int l = 0; l < 4; l++) {
            float e = __expf(sc[r][l] - m[r]);
            sc[r][l] = e;
            acc += e;
        }
#pragma unroll
        for (int off = 32; off >= 1; off >>= 1) acc += __shfl_xor(acc, off);
        s[r] = acc;
    }
    if (lane == 0) {
#pragma unroll
        for (int r = 0; r < 12; r++) red[wave * 12 + r] = s[r];
    }
    __syncthreads();
#pragma unroll
    for (int r = 0; r < 12; r++) {
        float v = red[r];
#pragma unroll
        for (int w = 1; w < 8; w++) v += red[w * 12 + r];
        s[r] = 1.0f / v;
    }

    // ---- normalized float4 writes, lane-contiguous per r
    const size_t obase = (size_t)b * R_ * N_;
#pragma unroll
    for (int r = 0; r < 12; r++) {
        const float inv = s[r];
        float4 v;
        v.x = sc[r][0] * inv;
        v.y = sc[r][1] * inv;
        v.z = sc[r][2] * inv;
        v.w = sc[r][3] * inv;
        *reinterpret_cast<float4*>(&out[obase + (size_t)r * N_ + n0]) = v;
    }
}

// ---------------------------------------------------------------------------
extern "C" void kernel_launch(void* const* d_in, const int* in_sizes, int n_in,
                              void* d_out, int out_size, void* d_ws, size_t ws_size,
                              hipStream_t stream) {
    const float* rss  = (const float*)d_in[0];
    const float* ledf = (const float*)d_in[1];
    const float* ledp = (const float*)d_in[2];
    const float* prevp= (const float*)d_in[3];
    const int*   mask = (const int*)  d_in[4];
    const float* Wg1  = (const float*)d_in[5];
    const float* bg1  = (const float*)d_in[6];
    const float* Wg2  = (const float*)d_in[7];
    const float* bg2  = (const float*)d_in[8];
    const float* Wq1  = (const float*)d_in[9];
    const float* bq1  = (const float*)d_in[10];
    const float* Wq2  = (const float*)d_in[11];
    const float* bq2  = (const float*)d_in[12];
    const float* Wk1  = (const float*)d_in[13];
    const float* bk1  = (const float*)d_in[14];
    const float* Wk2  = (const float*)d_in[15];
    const float* bk2  = (const float*)d_in[16];
    const float* sigp = (const float*)d_in[17];

    float* out = (float*)d_out;
    float* inten = out + (size_t)B_ * R_ * N_;   // intensity_weight [B,R] tail

    float* qp = (float*)d_ws;                    // [B*R,32]
    float* cc = qp + (size_t)B_ * R_ * 32;       // [B*R]
    int* maskbits = (int*)(cc + B_ * R_);        // [N]  (16B-aligned)

    prep_kernel<<<(B_ * R_ + 255) / 256, 256, 0, stream>>>(
        rss, Wg1, bg1, Wg2, bg2, Wq1, bq1, Wq2, bq2, Wk2, bk2, mask,
        qp, cc, maskbits, inten);

    main_kernel<<<B_, 512, 0, stream>>>(
        ledf, ledp, prevp, maskbits, Wk1, bk1, qp, cc, sigp, out);
}

// Round 6
// 522.819 us; speedup vs baseline: 1.0075x; 1.0075x over previous
//
#include <hip/hip_runtime.h>
#include <math.h>
#include <float.h>

#define B_ 1024
#define R_ 12
#define N_ 2048

typedef float floatx4 __attribute__((ext_vector_type(4)));

// ---------------------------------------------------------------------------
// Kernel 1: per (b,r) — intensity gate, Q MLP, fold Wk2/bk2 into the query:
//   Qp[32] = Wk2 @ Q,  c = Q . bk2.   Writes intensity to d_out tail.
// Threads with idx < N_ additionally pack the 12 freq-mask bits per LED.
// __launch_bounds__(256,1): allow high VGPR so Qp/h1 stay in registers.
// ---------------------------------------------------------------------------
__global__ void __launch_bounds__(256, 1) prep_kernel(
    const float* __restrict__ rss,                       // [B*R]
    const float* __restrict__ Wg1, const float* __restrict__ bg1,
    const float* __restrict__ Wg2, const float* __restrict__ bg2,
    const float* __restrict__ Wq1, const float* __restrict__ bq1,
    const float* __restrict__ Wq2, const float* __restrict__ bq2,
    const float* __restrict__ Wk2, const float* __restrict__ bk2,
    const int*   __restrict__ mask,                      // [R,N]
    float* __restrict__ qp,                              // [B*R, 32]
    float* __restrict__ cc,                              // [B*R]
    int*   __restrict__ maskbits,                        // [N]
    float* __restrict__ inten_out)                       // [B*R]
{
    int idx = blockIdx.x * 256 + threadIdx.x;
    if (idx >= B_ * R_) return;

    // ---- pack freq mask bits (one pass, threads 0..N-1)
    if (idx < N_) {
        int bits = 0;
#pragma unroll
        for (int r = 0; r < R_; r++) bits |= (mask[r * N_ + idx] != 0) << r;
        maskbits[idx] = bits;
    }

    float x = rss[idx];
    float hard = (x > 0.5f) ? 1.0f : 0.0f;

    // gate MLP 1->16->1 + sigmoid
    float s2 = bg2[0];
#pragma unroll
    for (int i = 0; i < 16; i++) {
        float t = fmaxf(x * Wg1[i] + bg1[i], 0.0f);
        s2 += t * Wg2[i];
    }
    float gate = 1.0f / (1.0f + __expf(-s2));
    float iw = hard * gate;
    inten_out[idx] = iw;

    float xm = x * iw;

    // Q hidden 1->32
    float h1[32];
#pragma unroll
    for (int i = 0; i < 32; i++) h1[i] = fmaxf(xm * Wq1[i] + bq1[i], 0.0f);

    // q[d] = h1 . Wq2[:,d] + bq2[d];  Qp[j] = sum_d Wk2[j,d]*q[d];  c = q.bk2
    float Qp[32];
#pragma unroll
    for (int j = 0; j < 32; j++) Qp[j] = 0.0f;
    float c = 0.0f;
#pragma unroll 4
    for (int d = 0; d < 64; d++) {
        float q = bq2[d];
#pragma unroll
        for (int i = 0; i < 32; i++) q += h1[i] * Wq2[i * 64 + d];
        c += q * bk2[d];
#pragma unroll
        for (int j = 0; j < 32; j++) Qp[j] += Wk2[j * 64 + d] * q;
    }

    float* o = qp + (size_t)idx * 32;
#pragma unroll
    for (int j = 0; j < 32; j++) o[j] = Qp[j];
    cc[idx] = c;
}

// ---------------------------------------------------------------------------
// Kernel 2: one block per batch b.  512 threads; thread t owns LEDs
// n = 4t..4t+3 (all accesses float4/int4).  Weights / Qp / c are read with
// wave-uniform indices -> s_load / SGPR operands; each weight value is loaded
// ONCE and feeds 4 independent FMA chains (j outer, LED innermost).
// Live set ~120 VGPR; __launch_bounds__(512,2) caps at 256 so nothing spills.
// ---------------------------------------------------------------------------
__global__ void __launch_bounds__(512, 2) main_kernel(
    const float* __restrict__ ledf,   // [B,N,8]
    const float* __restrict__ ledp,   // [B,N,3]
    const float* __restrict__ prevp,  // [B,3]
    const int*   __restrict__ maskbits, // [N]
    const float* __restrict__ Wk1,    // [11,32]
    const float* __restrict__ bk1,    // [32]
    const float* __restrict__ qp,     // [B*R,32]
    const float* __restrict__ cc,     // [B*R]
    const float* __restrict__ sigp,   // [1]
    float* __restrict__ out)          // [B,R,N]
{
    const int b = blockIdx.x;
    const int tid = threadIdx.x;
    const int lane = tid & 63;
    const int wave = tid >> 6;
    const int n0 = tid * 4;

    __shared__ float red[8 * 12];     // softmax reduction scratch only

    const float* __restrict__ qpb = qp + (size_t)b * 12 * 32;  // uniform base
    const float* __restrict__ ccb = cc + b * 12;

    const float sig = sigp[0];
    const float nf = -0.5f / (sig * sig);
    const float p0 = prevp[b * 3 + 0];
    const float p1 = prevp[b * 3 + 1];
    const float p2 = prevp[b * 3 + 2];

    // ---- vectorized per-thread loads (contiguous 4 LEDs)
    const float4* pf = reinterpret_cast<const float4*>(ledf + ((size_t)b * N_ + n0) * 8);
    const float4* pp = reinterpret_cast<const float4*>(ledp + ((size_t)b * N_ + n0) * 3);
    const float4 pa = pp[0], pb = pp[1], pc = pp[2];
    const float px[4] = {pa.x, pa.w, pb.z, pc.y};
    const float py[4] = {pa.y, pb.x, pb.w, pc.z};
    const float pz[4] = {pa.z, pb.y, pc.x, pc.w};
    const int4 mb4 = *reinterpret_cast<const int4*>(maskbits + n0);
    const int mbits[4] = {mb4.x, mb4.y, mb4.z, mb4.w};

    // features for all 4 LEDs stay live (44 regs)
    float xf[4][11];
#pragma unroll
    for (int l = 0; l < 4; l++) {
        const float4 f0 = pf[l * 2];
        const float4 f1 = pf[l * 2 + 1];
        xf[l][0] = f0.x; xf[l][1] = f0.y; xf[l][2] = f0.z; xf[l][3] = f0.w;
        xf[l][4] = f1.x; xf[l][5] = f1.y; xf[l][6] = f1.z; xf[l][7] = f1.w;
        xf[l][8] = px[l]; xf[l][9] = py[l]; xf[l][10] = pz[l];
    }

    // score accumulators a[r][l], seeded with c_r + bias_l
    float a[12][4];
#pragma unroll
    for (int l = 0; l < 4; l++) {
        const float dx = p0 - px[l], dy = p1 - py[l], dz = p2 - pz[l];
        const float bias = nf * (dx * dx + dy * dy + dz * dz);
#pragma unroll
        for (int r = 0; r < 12; r++) a[r][l] = ccb[r] + bias;
    }

    // ---- fused K-MLP + projected-query dots: j outer, each weight loaded
    //      once and reused across the 4 LEDs
#pragma unroll
    for (int j = 0; j < 32; j++) {
        const float bj = bk1[j];                             // uniform
        float hj[4] = {bj, bj, bj, bj};
#pragma unroll
        for (int t = 0; t < 11; t++) {
            const float w = Wk1[t * 32 + j];                 // uniform, 1 load
#pragma unroll
            for (int l = 0; l < 4; l++) hj[l] += xf[l][t] * w;
        }
#pragma unroll
        for (int l = 0; l < 4; l++) hj[l] = fmaxf(hj[l], 0.0f);
#pragma unroll
        for (int r = 0; r < 12; r++) {
            const float qw = qpb[r * 32 + j];                // uniform, 1 load
#pragma unroll
            for (int l = 0; l < 4; l++) a[r][l] += hj[l] * qw;
        }
    }

    // ---- apply freq mask
    float sc[12][4];
#pragma unroll
    for (int r = 0; r < 12; r++)
#pragma unroll
        for (int l = 0; l < 4; l++)
            sc[r][l] = ((mbits[l] >> r) & 1) ? a[r][l] : -FLT_MAX;

    // ---- block-wide max per row r
    float m[12];
#pragma unroll
    for (int r = 0; r < 12; r++) {
        float v = fmaxf(fmaxf(sc[r][0], sc[r][1]), fmaxf(sc[r][2], sc[r][3]));
#pragma unroll
        for (int off = 32; off >= 1; off >>= 1) v = fmaxf(v, __shfl_xor(v, off));
        m[r] = v;
    }
    if (lane == 0) {
#pragma unroll
        for (int r = 0; r < 12; r++) red[wave * 12 + r] = m[r];
    }
    __syncthreads();
#pragma unroll
    for (int r = 0; r < 12; r++) {
        float v = red[r];
#pragma unroll
        for (int w = 1; w < 8; w++) v = fmaxf(v, red[w * 12 + r]);
        m[r] = v;
    }
    __syncthreads();  // red about to be reused

    // ---- exp + block-wide sum per row r
    float s[12];
#pragma unroll
    for (int r = 0; r < 12; r++) {
        float acc = 0.0f;
#pragma unroll
        for (int l = 0; l < 4; l++) {
            float e = __expf(sc[r][l] - m[r]);
            sc[r][l] = e;
            acc += e;
        }
#pragma unroll
        for (int off = 32; off >= 1; off >>= 1) acc += __shfl_xor(acc, off);
        s[r] = acc;
    }
    if (lane == 0) {
#pragma unroll
        for (int r = 0; r < 12; r++) red[wave * 12 + r] = s[r];
    }
    __syncthreads();
#pragma unroll
    for (int r = 0; r < 12; r++) {
        float v = red[r];
#pragma unroll
        for (int w = 1; w < 8; w++) v += red[w * 12 + r];
        s[r] = 1.0f / v;
    }

    // ---- normalized vec4 nontemporal writes, lane-contiguous per r
    const size_t obase = (size_t)b * R_ * N_;
#pragma unroll
    for (int r = 0; r < 12; r++) {
        const float inv = s[r];
        floatx4 v;
        v.x = sc[r][0] * inv;
        v.y = sc[r][1] * inv;
        v.z = sc[r][2] * inv;
        v.w = sc[r][3] * inv;
        __builtin_nontemporal_store(v, reinterpret_cast<floatx4*>(
            &out[obase + (size_t)r * N_ + n0]));
    }
}

// ---------------------------------------------------------------------------
extern "C" void kernel_launch(void* const* d_in, const int* in_sizes, int n_in,
                              void* d_out, int out_size, void* d_ws, size_t ws_size,
                              hipStream_t stream) {
    const float* rss  = (const float*)d_in[0];
    const float* ledf = (const float*)d_in[1];
    const float* ledp = (const float*)d_in[2];
    const float* prevp= (const float*)d_in[3];
    const int*   mask = (const int*)  d_in[4];
    const float* Wg1  = (const float*)d_in[5];
    const float* bg1  = (const float*)d_in[6];
    const float* Wg2  = (const float*)d_in[7];
    const float* bg2  = (const float*)d_in[8];
    const float* Wq1  = (const float*)d_in[9];
    const float* bq1  = (const float*)d_in[10];
    const float* Wq2  = (const float*)d_in[11];
    const float* bq2  = (const float*)d_in[12];
    const float* Wk1  = (const float*)d_in[13];
    const float* bk1  = (const float*)d_in[14];
    const float* Wk2  = (const float*)d_in[15];
    const float* bk2  = (const float*)d_in[16];
    const float* sigp = (const float*)d_in[17];

    float* out = (float*)d_out;
    float* inten = out + (size_t)B_ * R_ * N_;   // intensity_weight [B,R] tail

    float* qp = (float*)d_ws;                    // [B*R,32]
    float* cc = qp + (size_t)B_ * R_ * 32;       // [B*R]
    int* maskbits = (int*)(cc + B_ * R_);        // [N]  (16B-aligned)

    prep_kernel<<<(B_ * R_ + 255) / 256, 256, 0, stream>>>(
        rss, Wg1, bg1, Wg2, bg2, Wq1, bq1, Wq2, bq2, Wk2, bk2, mask,
        qp, cc, maskbits, inten);

    main_kernel<<<B_, 512, 0, stream>>>(
        ledf, ledp, prevp, maskbits, Wk1, bk1, qp, cc, sigp, out);
}

// Round 7
// 279.743 us; speedup vs baseline: 1.8829x; 1.8689x over previous
//
#include <hip/hip_runtime.h>
#include <math.h>
#include <float.h>

#define B_ 1024
#define R_ 12
#define N_ 2048

typedef float floatx4 __attribute__((ext_vector_type(4)));

#define FOR_R(OP) OP(0) OP(1) OP(2) OP(3) OP(4) OP(5) OP(6) OP(7) OP(8) OP(9) OP(10) OP(11)

// ---------------------------------------------------------------------------
// const_kernel (1 block, 1024 thr): fold Wk2/bk2/bq2 into prep constants:
//   M[i,j] = Wq2[i,:] . Wk2[j,:]   (32x32)
//   v[j]   = Wk2[j,:] . bq2        u[i] = Wq2[i,:] . bk2       k0 = bq2 . bk2
// ---------------------------------------------------------------------------
__global__ void __launch_bounds__(1024) const_kernel(
    const float* __restrict__ Wq2, const float* __restrict__ bq2,
    const float* __restrict__ Wk2, const float* __restrict__ bk2,
    float* __restrict__ Mmat, float* __restrict__ uvec,
    float* __restrict__ vvec, float* __restrict__ k0p)
{
    const int t = threadIdx.x;
    const int i = t >> 5, j = t & 31;
    float m = 0.0f;
    for (int d = 0; d < 64; d++) m += Wq2[i * 64 + d] * Wk2[j * 64 + d];
    Mmat[t] = m;
    if (t < 32) {
        float v = 0.0f;
        for (int d = 0; d < 64; d++) v += Wk2[t * 64 + d] * bq2[d];
        vvec[t] = v;
    } else if (t < 64) {
        float u = 0.0f;
        for (int d = 0; d < 64; d++) u += Wq2[(t - 32) * 64 + d] * bk2[d];
        uvec[t - 32] = u;
    } else if (t == 64) {
        float k = 0.0f;
        for (int d = 0; d < 64; d++) k += bq2[d] * bk2[d];
        k0p[0] = k;
    }
}

// ---------------------------------------------------------------------------
// prep_kernel: 32 lanes per (b,r) pair; lane j owns Qp_j.  NO private arrays —
// h1_i is a transient scalar recomputed in the i-loop.  Also packs mask bits.
// ---------------------------------------------------------------------------
__global__ void __launch_bounds__(256) prep_kernel(
    const float* __restrict__ rss,                       // [B*R]
    const float* __restrict__ Wg1, const float* __restrict__ bg1,
    const float* __restrict__ Wg2, const float* __restrict__ bg2,
    const float* __restrict__ Wq1, const float* __restrict__ bq1,
    const float* __restrict__ Mmat, const float* __restrict__ uvec,
    const float* __restrict__ vvec, const float* __restrict__ k0p,
    const int*   __restrict__ mask,                      // [R,N]
    float* __restrict__ qp,                              // [B*R, 32]
    float* __restrict__ cc,                              // [B*R]
    int*   __restrict__ maskbits,                        // [N]
    float* __restrict__ inten_out)                       // [B*R]
{
    const int gt = blockIdx.x * 256 + threadIdx.x;

    // ---- pack freq mask bits (first N_ threads)
    if (gt < N_) {
        int bits = 0;
#pragma unroll
        for (int r = 0; r < R_; r++) bits |= (mask[r * N_ + gt] != 0) << r;
        maskbits[gt] = bits;
    }

    const int idx = gt >> 5;          // (b,r) pair
    const int j = gt & 31;
    if (idx >= B_ * R_) return;

    const float x = rss[idx];
    const float hard = (x > 0.5f) ? 1.0f : 0.0f;

    // gate MLP 1->16->1 + sigmoid (redundant across 32 lanes; transient scalars)
    float s2 = bg2[0];
    for (int i = 0; i < 16; i++)
        s2 += fmaxf(x * Wg1[i] + bg1[i], 0.0f) * Wg2[i];
    const float gate = 1.0f / (1.0f + __expf(-s2));
    const float iw = hard * gate;
    const float xm = x * iw;

    // Qp_j = v_j + sum_i h1_i M[i,j];  c = k0 + sum_i h1_i u_i
    float Qpj = vvec[j];
    float c = k0p[0];
    for (int i = 0; i < 32; i++) {
        const float h = fmaxf(xm * Wq1[i] + bq1[i], 0.0f);
        Qpj += h * Mmat[i * 32 + j];    // lane-consecutive j -> coalesced
        c   += h * uvec[i];
    }

    qp[(size_t)idx * 32 + j] = Qpj;
    if (j == 0) {
        cc[idx] = c;
        inten_out[idx] = iw;
    }
}

// ---------------------------------------------------------------------------
// main_kernel: one block per batch b, 512 threads; thread t owns LEDs
// 4t..4t+3 held as LANES of ext_vector floatx4.  All thread-private state is
// NAMED variables (X0..X10, A0..A11) -> SROA always succeeds, zero scratch.
// The j-loop indexes only global (uniform -> s_load) memory.
// ---------------------------------------------------------------------------
__global__ void __launch_bounds__(512, 2) main_kernel(
    const float* __restrict__ ledf,     // [B,N,8]
    const float* __restrict__ ledp,     // [B,N,3]
    const float* __restrict__ prevp,    // [B,3]
    const int*   __restrict__ maskbits, // [N]
    const float* __restrict__ Wk1,      // [11,32]
    const float* __restrict__ bk1,      // [32]
    const float* __restrict__ qp,       // [B*R,32]
    const float* __restrict__ cc,       // [B*R]
    const float* __restrict__ sigp,     // [1]
    float* __restrict__ out)            // [B,R,N]
{
    const int b = blockIdx.x;
    const int tid = threadIdx.x;
    const int lane = tid & 63;
    const int wave = tid >> 6;
    const int n0 = tid * 4;

    __shared__ float red[8 * 12];

    const float* __restrict__ qpb = qp + (size_t)b * 12 * 32;
    const float* __restrict__ ccb = cc + b * 12;

    const float sig = sigp[0];
    const float nfc = -0.5f / (sig * sig);
    const float p0 = prevp[b * 3 + 0];
    const float p1 = prevp[b * 3 + 1];
    const float p2 = prevp[b * 3 + 2];

    // ---- vectorized loads: 4 consecutive LEDs per thread
    const floatx4* pf = reinterpret_cast<const floatx4*>(ledf + ((size_t)b * N_ + n0) * 8);
    const floatx4* pp4 = reinterpret_cast<const floatx4*>(ledp + ((size_t)b * N_ + n0) * 3);
    const floatx4 F0 = pf[0], F1 = pf[1], F2 = pf[2], F3 = pf[3];
    const floatx4 F4 = pf[4], F5 = pf[5], F6 = pf[6], F7 = pf[7];
    const floatx4 pa = pp4[0], pb = pp4[1], pc = pp4[2];
    const int4 mb = *reinterpret_cast<const int4*>(maskbits + n0);

    // transpose features to across-LED vectors (named, never indexed)
    const floatx4 X0 = {F0.x, F2.x, F4.x, F6.x};
    const floatx4 X1 = {F0.y, F2.y, F4.y, F6.y};
    const floatx4 X2 = {F0.z, F2.z, F4.z, F6.z};
    const floatx4 X3 = {F0.w, F2.w, F4.w, F6.w};
    const floatx4 X4 = {F1.x, F3.x, F5.x, F7.x};
    const floatx4 X5 = {F1.y, F3.y, F5.y, F7.y};
    const floatx4 X6 = {F1.z, F3.z, F5.z, F7.z};
    const floatx4 X7 = {F1.w, F3.w, F5.w, F7.w};
    const floatx4 X8 = {pa.x, pa.w, pb.z, pc.y};   // pos x
    const floatx4 X9 = {pa.y, pb.x, pb.w, pc.z};   // pos y
    const floatx4 X10 = {pa.z, pb.y, pc.x, pc.w};  // pos z

    const floatx4 DX = p0 - X8, DY = p1 - X9, DZ = p2 - X10;
    const floatx4 BIAS = nfc * (DX * DX + DY * DY + DZ * DZ);

#define INIT_R(r) floatx4 A##r = BIAS + ccb[r];
    FOR_R(INIT_R)

    // ---- fused K-MLP + projected-query dots (j rolled; global-only indexing)
    for (int j = 0; j < 32; j++) {
        const float bj = bk1[j];
        floatx4 H = {bj, bj, bj, bj};
        H += X0 * Wk1[0 * 32 + j];
        H += X1 * Wk1[1 * 32 + j];
        H += X2 * Wk1[2 * 32 + j];
        H += X3 * Wk1[3 * 32 + j];
        H += X4 * Wk1[4 * 32 + j];
        H += X5 * Wk1[5 * 32 + j];
        H += X6 * Wk1[6 * 32 + j];
        H += X7 * Wk1[7 * 32 + j];
        H += X8 * Wk1[8 * 32 + j];
        H += X9 * Wk1[9 * 32 + j];
        H += X10 * Wk1[10 * 32 + j];
        H.x = fmaxf(H.x, 0.0f);
        H.y = fmaxf(H.y, 0.0f);
        H.z = fmaxf(H.z, 0.0f);
        H.w = fmaxf(H.w, 0.0f);
#define ACC_R(r) A##r += H * qpb[r * 32 + j];
        FOR_R(ACC_R)
    }

    // ---- freq mask
#define MASK_R(r)                                      \
    A##r.x = ((mb.x >> r) & 1) ? A##r.x : -FLT_MAX;    \
    A##r.y = ((mb.y >> r) & 1) ? A##r.y : -FLT_MAX;    \
    A##r.z = ((mb.z >> r) & 1) ? A##r.z : -FLT_MAX;    \
    A##r.w = ((mb.w >> r) & 1) ? A##r.w : -FLT_MAX;
    FOR_R(MASK_R)

    // ---- block max per row
#define WMAX_R(r) {                                                     \
    float v = fmaxf(fmaxf(A##r.x, A##r.y), fmaxf(A##r.z, A##r.w));      \
    _Pragma("unroll")                                                   \
    for (int off = 32; off >= 1; off >>= 1) v = fmaxf(v, __shfl_xor(v, off)); \
    if (lane == 0) red[wave * 12 + r] = v; }
    FOR_R(WMAX_R)
    __syncthreads();
#define FMAX_R(r) float M##r = red[r];                                  \
    { _Pragma("unroll")                                                 \
      for (int w = 1; w < 8; w++) M##r = fmaxf(M##r, red[w * 12 + r]); }
    FOR_R(FMAX_R)
    __syncthreads();

    // ---- exp + block sum per row
#define EXP_R(r) {                                                      \
    A##r.x = __expf(A##r.x - M##r); A##r.y = __expf(A##r.y - M##r);     \
    A##r.z = __expf(A##r.z - M##r); A##r.w = __expf(A##r.w - M##r);     \
    float v = (A##r.x + A##r.y) + (A##r.z + A##r.w);                    \
    _Pragma("unroll")                                                   \
    for (int off = 32; off >= 1; off >>= 1) v += __shfl_xor(v, off);    \
    if (lane == 0) red[wave * 12 + r] = v; }
    FOR_R(EXP_R)
    __syncthreads();
#define FSUM_R(r) float S##r = red[r];                                  \
    { _Pragma("unroll")                                                 \
      for (int w = 1; w < 8; w++) S##r += red[w * 12 + r]; }            \
    S##r = 1.0f / S##r;
    FOR_R(FSUM_R)

    // ---- normalized vec4 nontemporal stores
    float* outp = out + (size_t)b * R_ * N_ + n0;
#define STORE_R(r) {                                                    \
    floatx4 v = A##r * S##r;                                            \
    __builtin_nontemporal_store(v, reinterpret_cast<floatx4*>(outp + (size_t)r * N_)); }
    FOR_R(STORE_R)
}

// ---------------------------------------------------------------------------
extern "C" void kernel_launch(void* const* d_in, const int* in_sizes, int n_in,
                              void* d_out, int out_size, void* d_ws, size_t ws_size,
                              hipStream_t stream) {
    const float* rss  = (const float*)d_in[0];
    const float* ledf = (const float*)d_in[1];
    const float* ledp = (const float*)d_in[2];
    const float* prevp= (const float*)d_in[3];
    const int*   mask = (const int*)  d_in[4];
    const float* Wg1  = (const float*)d_in[5];
    const float* bg1  = (const float*)d_in[6];
    const float* Wg2  = (const float*)d_in[7];
    const float* bg2  = (const float*)d_in[8];
    const float* Wq1  = (const float*)d_in[9];
    const float* bq1  = (const float*)d_in[10];
    const float* Wq2  = (const float*)d_in[11];
    const float* bq2  = (const float*)d_in[12];
    const float* Wk1  = (const float*)d_in[13];
    const float* bk1  = (const float*)d_in[14];
    const float* Wk2  = (const float*)d_in[15];
    const float* bk2  = (const float*)d_in[16];
    const float* sigp = (const float*)d_in[17];

    float* out = (float*)d_out;
    float* inten = out + (size_t)B_ * R_ * N_;     // intensity_weight [B,R] tail

    float* qp       = (float*)d_ws;                // [B*R,32]
    float* cc       = qp + (size_t)B_ * R_ * 32;   // [B*R]
    int*   maskbits = (int*)(cc + B_ * R_);        // [N]
    float* Mmat     = (float*)(maskbits + N_);     // [32,32]
    float* uvec     = Mmat + 1024;                 // [32]
    float* vvec     = uvec + 32;                   // [32]
    float* k0p      = vvec + 32;                   // [1]

    const_kernel<<<1, 1024, 0, stream>>>(Wq2, bq2, Wk2, bk2, Mmat, uvec, vvec, k0p);

    prep_kernel<<<(B_ * R_ * 32 + 255) / 256, 256, 0, stream>>>(
        rss, Wg1, bg1, Wg2, bg2, Wq1, bq1,
        Mmat, uvec, vvec, k0p, mask, qp, cc, maskbits, inten);

    main_kernel<<<B_, 512, 0, stream>>>(
        ledf, ledp, prevp, maskbits, Wk1, bk1, qp, cc, sigp, out);
}